// Round 1
// 339.338 us; speedup vs baseline: 1.1570x; 1.1570x over previous
//
#include <hip/hip_runtime.h>

// ChebNet K=3, W-first form: ChebConv(H) = H@(W0-W2) + S·(H@W1 + 2·S·(H@W2)).
// Round 14: dense layers moved to MFMA (v_mfma_f32_16x16x32_f16, fp32 accum).
// Weights pre-transposed/swizzled to fp16 by k_wprep; x/H reg-staged f32->f16
// into XOR-swizzled LDS (slot ^= row&7 -> conflict-free ds_read_b128 frags).
// fp16 input rounding (~3e-4 rel) is far below existing bf16 intermediate
// noise, so numerics are preserved. Dense kernels become write-BW-bound.

static constexpr int BLK = 256;
static constexpr int SCAN_CHUNK = 256;
static constexpr int ROWB = 256;
static constexpr int RB_SHIFT = 8;
static constexpr int BCAP = 6144;
static constexpr int CHUNK = 8192;

typedef _Float16 f16x8 __attribute__((ext_vector_type(8)));
typedef float f32x4 __attribute__((ext_vector_type(4)));

__device__ __forceinline__ unsigned rotl32(unsigned x, int r) {
    return (x << r) | (x >> (32 - r));
}

// JAX partitionable threefry word for element i:
// (b1,b2) = threefry2x32(key=(0,42), counter=(0,i)); word = b1 ^ b2.
__device__ __forceinline__ unsigned tf_word(unsigned i) {
    const unsigned ks0 = 0u;
    const unsigned ks1 = 42u;
    const unsigned ks2 = 0u ^ 42u ^ 0x1BD11BDAu;
    unsigned x0 = 0u + ks0;
    unsigned x1 = i + ks1;
#define TF_RND(r) { x0 += x1; x1 = rotl32(x1, (r)); x1 ^= x0; }
    TF_RND(13) TF_RND(15) TF_RND(26) TF_RND(6)
    x0 += ks1; x1 += ks2 + 1u;
    TF_RND(17) TF_RND(29) TF_RND(16) TF_RND(24)
    x0 += ks2; x1 += ks0 + 2u;
    TF_RND(13) TF_RND(15) TF_RND(26) TF_RND(6)
    x0 += ks0; x1 += ks1 + 3u;
    TF_RND(17) TF_RND(29) TF_RND(16) TF_RND(24)
    x0 += ks1; x1 += ks2 + 4u;
    TF_RND(13) TF_RND(15) TF_RND(26) TF_RND(6)
    x0 += ks2; x1 += ks0 + 5u;
#undef TF_RND
    return x0 ^ x1;
}

// bf16 pack/unpack
__device__ __forceinline__ float lo16(unsigned u) {
    union { unsigned x; float f; } c; c.x = u << 16; return c.f;
}
__device__ __forceinline__ float hi16(unsigned u) {
    union { unsigned x; float f; } c; c.x = u & 0xFFFF0000u; return c.f;
}
__device__ __forceinline__ unsigned short f2b(float f) {
    union { float f; unsigned u; } c; c.f = f;
    unsigned r = (c.u + 0x7FFFu + ((c.u >> 16) & 1u)) >> 16;
    return (unsigned short)r;
}
__device__ __forceinline__ unsigned pack2(float a, float b) {
    return (unsigned)f2b(a) | ((unsigned)f2b(b) << 16);
}

__global__ void k_detect(const int* __restrict__ ei, int* __restrict__ flags) {
    __shared__ int cnt_nz;
    int t = threadIdx.x;
    if (t == 0) cnt_nz = 0;
    __syncthreads();
    if (ei[2 * t + 1] != 0) atomicAdd(&cnt_nz, 1);
    __syncthreads();
    if (t == 0) flags[0] = (cnt_nz == 0) ? 1 : 0;
}

// Pass 1: bin edges into row-buckets, LDS-staged for coalesced writes.
__global__ void __launch_bounds__(256) k_bin(const int* __restrict__ ei, int E,
                                             const int* __restrict__ flags,
                                             int* __restrict__ bcnt,
                                             unsigned* __restrict__ bdata, int NB) {
    __shared__ unsigned sval[CHUNK];
    __shared__ unsigned short sbkt[CHUNK];
    __shared__ int h[512], ex[512], cur[512], basep[512];
    int t = threadIdx.x;
    int start = blockIdx.x * CHUNK;
    int lim = min(CHUNK, E - start);
    bool i64 = flags[0] != 0;
    h[t] = 0; h[t + 256] = 0;
    __syncthreads();
    unsigned vv[32];
    unsigned short bb_[32];
#pragma unroll
    for (int k = 0; k < 32; ++k) {
        int idx = k * 256 + t;
        int e = start + idx;
        if (idx < lim) {
            int r, c;
            if (i64) { r = ei[2 * e]; c = ei[2 * (E + e)]; }
            else     { r = ei[e];     c = ei[E + e]; }
            int b = r >> RB_SHIFT;
            vv[k] = ((unsigned)(r & (ROWB - 1)) << 17) | (unsigned)c;
            bb_[k] = (unsigned short)b;
            atomicAdd(&h[b], 1);
        } else {
            bb_[k] = 0xFFFF;
        }
    }
    __syncthreads();
    int i0 = t, i1 = t + 256;
    ex[i0] = h[i0]; ex[i1] = h[i1];
    __syncthreads();
    for (int off = 1; off < 512; off <<= 1) {
        int v0 = (i0 >= off) ? ex[i0 - off] : 0;
        int v1 = (i1 >= off) ? ex[i1 - off] : 0;
        __syncthreads();
        ex[i0] += v0; ex[i1] += v1;
        __syncthreads();
    }
    int e0 = ex[i0] - h[i0], e1 = ex[i1] - h[i1];
    __syncthreads();
    ex[i0] = e0; cur[i0] = e0;
    ex[i1] = e1; cur[i1] = e1;
    if (i0 < NB && h[i0] > 0) basep[i0] = atomicAdd(&bcnt[i0], h[i0]);
    if (i1 < NB && h[i1] > 0) basep[i1] = atomicAdd(&bcnt[i1], h[i1]);
    __syncthreads();
#pragma unroll
    for (int k = 0; k < 32; ++k) {
        if (bb_[k] != 0xFFFF) {
            int p = atomicAdd(&cur[bb_[k]], 1);
            sval[p] = vv[k];
            sbkt[p] = bb_[k];
        }
    }
    __syncthreads();
    for (int i = t; i < lim; i += 256) {
        int b = sbkt[i];
        int gpos = basep[b] + (i - ex[b]);
        if (gpos < BCAP) bdata[(size_t)b * BCAP + gpos] = sval[i];
    }
}

__global__ void __launch_bounds__(256) k_hist2(const unsigned* __restrict__ bdata,
                                               const int* __restrict__ bcnt,
                                               int N, int* __restrict__ deg) {
    __shared__ int h[ROWB];
    int t = threadIdx.x, b = blockIdx.x;
    h[t] = 0;
    __syncthreads();
    int cnt = min(bcnt[b], BCAP);
    for (int i = t; i < cnt; i += 256)
        atomicAdd(&h[bdata[(size_t)b * BCAP + i] >> 17], 1);
    __syncthreads();
    int r = b * ROWB + t;
    if (r < N) deg[r] = h[t];
}

__global__ void k_dinv(const int* __restrict__ deg, int N, float* __restrict__ dinv) {
    int v = blockIdx.x * blockDim.x + threadIdx.x;
    if (v < N) {
        int d = deg[v];
        dinv[v] = (d > 0) ? (1.0f / sqrtf((float)d)) : 0.0f;
    }
}

__global__ void k_scanA(const int* __restrict__ deg, int N, int* __restrict__ blk_sum) {
    __shared__ int lds[SCAN_CHUNK];
    int i = blockIdx.x * SCAN_CHUNK + threadIdx.x;
    int v = (i < N) ? deg[i] : 0;
    lds[threadIdx.x] = v;
    __syncthreads();
    for (int off = SCAN_CHUNK / 2; off > 0; off >>= 1) {
        if (threadIdx.x < off) lds[threadIdx.x] += lds[threadIdx.x + off];
        __syncthreads();
    }
    if (threadIdx.x == 0) blk_sum[blockIdx.x] = lds[0];
}

__global__ void k_scanB(int* __restrict__ blk_sum, int nb) {
    __shared__ int lds[1024];
    int t = threadIdx.x;
    int v = (t < nb) ? blk_sum[t] : 0;
    lds[t] = v;
    __syncthreads();
    for (int off = 1; off < 1024; off <<= 1) {
        int val = (t >= off) ? lds[t - off] : 0;
        __syncthreads();
        lds[t] += val;
        __syncthreads();
    }
    if (t < nb) blk_sum[t] = lds[t] - v;
}

__global__ void k_scanC(const int* __restrict__ deg, int N, int E,
                        const int* __restrict__ blk_sum, int* __restrict__ row_ptr) {
    __shared__ int lds[SCAN_CHUNK];
    int t = threadIdx.x;
    int i = blockIdx.x * SCAN_CHUNK + t;
    int v = (i < N) ? deg[i] : 0;
    lds[t] = v;
    __syncthreads();
    for (int off = 1; off < SCAN_CHUNK; off <<= 1) {
        int val = (t >= off) ? lds[t - off] : 0;
        __syncthreads();
        lds[t] += val;
        __syncthreads();
    }
    if (i < N) row_ptr[i] = blk_sum[blockIdx.x] + lds[t] - v;
    if (blockIdx.x == gridDim.x - 1 && t == SCAN_CHUNK - 1) row_ptr[N] = E;
}

__global__ void __launch_bounds__(256) k_place(const unsigned* __restrict__ bdata,
                                               const int* __restrict__ bcnt,
                                               const int* __restrict__ row_ptr,
                                               int N, int* __restrict__ sdst) {
    __shared__ int cur[ROWB];
    __shared__ int staged[BCAP];
    int t = threadIdx.x, b = blockIdx.x;
    int r0 = b * ROWB;
    int rbase = row_ptr[r0];
    int r = r0 + t;
    cur[t] = (r < N) ? (row_ptr[r] - rbase) : 0;
    __syncthreads();
    int cnt = min(bcnt[b], BCAP);
    for (int i = t; i < cnt; i += 256) {
        unsigned val = bdata[(size_t)b * BCAP + i];
        int p = atomicAdd(&cur[val >> 17], 1);
        staged[p] = (int)(val & 0x1FFFFu);
    }
    __syncthreads();
    for (int i = t; i < cnt; i += 256) sdst[rbase + i] = staged[i];
}

// Weight prep: fp16, transposed (col-major over output col), pre-XOR-swizzled
// LDS image. wt1: 192 cols x 64 k = [Wd=W1[0]-W1[2] | W1[1] | W1[2]].
// wt2: 96 cols x 64 k = [Wd2=W2[0]-W2[2] | W2[1] | W2[2]].
// dst ushort index within a row r6 = sw_slot*8+within; holds source slot
// (sw_slot ^ (col&7)) so a linear LDS copy lands the swizzle correctly.
__global__ void k_wprep(const float* __restrict__ W1, const float* __restrict__ W2,
                        unsigned short* __restrict__ wt1,
                        unsigned short* __restrict__ wt2) {
    int idx = blockIdx.x * 256 + threadIdx.x;
    if (idx < 12288) {
        int c = idx >> 6, r6 = idx & 63;
        int slot = (r6 >> 3) ^ (c & 7);
        int k = slot * 8 + (r6 & 7);
        float v;
        if (c < 64)       v = W1[k * 64 + c] - W1[8192 + k * 64 + c];
        else if (c < 128) v = W1[4096 + k * 64 + (c - 64)];
        else              v = W1[8192 + k * 64 + (c - 128)];
        union { _Float16 h; unsigned short u; } cv; cv.h = (_Float16)v;
        wt1[idx] = cv.u;
    } else {
        int j = idx - 12288;
        int c = j >> 6, r6 = j & 63;
        int slot = (r6 >> 3) ^ (c & 7);
        int k = slot * 8 + (r6 & 7);
        float v;
        if (c < 32)      v = W2[k * 32 + c] - W2[4096 + k * 32 + c];
        else if (c < 64) v = W2[2048 + k * 32 + (c - 32)];
        else             v = W2[4096 + k * 32 + (c - 64)];
        union { _Float16 h; unsigned short u; } cv; cv.h = (_Float16)v;
        wt2[j] = cv.u;
    }
}

// MFMA dense, layer 1. 128 nodes/block, 512 threads = 8 waves, each wave owns
// one 16-row M-tile x 12 N-tiles (192 cols = D | B16 | C16), K=64 in 2 steps
// of v_mfma_f32_16x16x32_f16. LDS: x16 [128][64] f16 swizzled (16 KB) +
// wt1 image (24 KB) + sb; bf16 outputs repacked through LDS for uint4 stores.
__global__ void __launch_bounds__(512) k_dense3(const float* __restrict__ x,
                                                const unsigned short* __restrict__ wt1,
                                                const float* __restrict__ b1,
                                                int N,
                                                unsigned short* __restrict__ B16,
                                                unsigned short* __restrict__ C16,
                                                float* __restrict__ D) {
    __shared__ unsigned short lds[20480] __attribute__((aligned(16)));  // x:[0,8192) W:[8192,20480)
    __shared__ float sb[64];
    int t = threadIdx.x;
    int v0 = blockIdx.x * 128;
    // stage weights (linear copy of pre-swizzled image)
    {
        const uint4* src = (const uint4*)wt1;
        uint4* dst = (uint4*)&lds[8192];
        for (int i = t; i < 1536; i += 512) dst[i] = src[i];
    }
    if (t < 64) sb[t] = b1[t];
    // stage x: thread t -> row t>>2, 16 floats at col (t&3)*16, f32->f16
    {
        int row = t >> 2, c0 = (t & 3) << 4;
        int v = min(v0 + row, N - 1);
        const float* xp = x + (size_t)v * 64 + c0;
        float4 f0 = *(const float4*)xp;
        float4 f1 = *(const float4*)(xp + 4);
        float4 f2 = *(const float4*)(xp + 8);
        float4 f3 = *(const float4*)(xp + 12);
        int key = row & 7;
        int s0 = c0 >> 3;
        f16x8 h0, h1;
        h0[0] = (_Float16)f0.x; h0[1] = (_Float16)f0.y;
        h0[2] = (_Float16)f0.z; h0[3] = (_Float16)f0.w;
        h0[4] = (_Float16)f1.x; h0[5] = (_Float16)f1.y;
        h0[6] = (_Float16)f1.z; h0[7] = (_Float16)f1.w;
        h1[0] = (_Float16)f2.x; h1[1] = (_Float16)f2.y;
        h1[2] = (_Float16)f2.z; h1[3] = (_Float16)f2.w;
        h1[4] = (_Float16)f3.x; h1[5] = (_Float16)f3.y;
        h1[6] = (_Float16)f3.z; h1[7] = (_Float16)f3.w;
        *(f16x8*)&lds[row * 64 + ((s0 ^ key) << 3)] = h0;
        *(f16x8*)&lds[row * 64 + (((s0 + 1) ^ key) << 3)] = h1;
    }
    __syncthreads();

    int w = t >> 6, l = t & 63;
    int lr = l & 15, lk = l >> 4;
    int key = lr & 7;                 // (row&7) == (col&7) == lr&7 for all tiles
    int arow = w * 16 + lr;
    f16x8 a0 = *(const f16x8*)&lds[arow * 64 + (((0 + lk) ^ key) << 3)];
    f16x8 a1 = *(const f16x8*)&lds[arow * 64 + (((4 + lk) ^ key) << 3)];
    f32x4 acc[12];
#pragma unroll
    for (int i = 0; i < 12; ++i) acc[i] = (f32x4){0.0f, 0.0f, 0.0f, 0.0f};
#pragma unroll
    for (int nt = 0; nt < 12; ++nt) {
        int bc = nt * 16 + lr;
        const unsigned short* wb = &lds[8192 + bc * 64];
        f16x8 b0 = *(const f16x8*)&wb[((0 + lk) ^ key) << 3];
        f16x8 b1v = *(const f16x8*)&wb[((4 + lk) ^ key) << 3];
        acc[nt] = __builtin_amdgcn_mfma_f32_16x16x32_f16(a0, b0, acc[nt], 0, 0, 0);
        acc[nt] = __builtin_amdgcn_mfma_f32_16x16x32_f16(a1, b1v, acc[nt], 0, 0, 0);
    }
    // D (f32, cols 0..63) + b1, direct stores
#pragma unroll
    for (int nt = 0; nt < 4; ++nt) {
        int col = nt * 16 + lr;
        float bv = sb[col];
#pragma unroll
        for (int r = 0; r < 4; ++r) {
            int v = v0 + w * 16 + lk * 4 + r;
            if (v < N) D[(size_t)v * 64 + col] = acc[nt][r] + bv;
        }
    }
    __syncthreads();
    // repack bf16 outputs (B16||C16) as [128][128] ushort in LDS
#pragma unroll
    for (int nt = 4; nt < 12; ++nt) {
        int col = (nt - 4) * 16 + lr;
#pragma unroll
        for (int r = 0; r < 4; ++r) {
            int vloc = w * 16 + lk * 4 + r;
            lds[vloc * 128 + col] = f2b(acc[nt][r]);
        }
    }
    __syncthreads();
#pragma unroll
    for (int q = 0; q < 4; ++q) {
        int i = q * 512 + t;          // 16B chunk id, 0..2047
        int row = i >> 4, ch = i & 15;
        int v = v0 + row;
        if (v < N) {
            uint4 val = *(const uint4*)&lds[i * 8];
            unsigned short* dst = (ch < 8)
                ? (B16 + (size_t)v * 64 + ch * 8)
                : (C16 + (size_t)v * 64 + (ch - 8) * 8);
            *(uint4*)dst = val;
        }
    }
}

// MFMA dense, layer 2. 128 nodes/block, 512 threads. 96 output cols:
// nt0-3 -> C[.,0:64] f32 (D0=H@(W2[0]-W2[2]) || D1=H@W2[1], in-place over H);
// nt4-5 -> D2=H@W2[2] bf16 into B16 pitch 32 (via LDS repack).
__global__ void __launch_bounds__(512) k_dense3b(const unsigned short* __restrict__ wt2,
                                                 int N,
                                                 unsigned short* __restrict__ B16,
                                                 float* __restrict__ C) {
    __shared__ unsigned short lds[14336] __attribute__((aligned(16)));  // x:[0,8192) W:[8192,14336)
    int t = threadIdx.x;
    int v0 = blockIdx.x * 128;
    {
        const uint4* src = (const uint4*)wt2;
        uint4* dst = (uint4*)&lds[8192];
        for (int i = t; i < 768; i += 512) dst[i] = src[i];
    }
    {
        int row = t >> 2, c0 = (t & 3) << 4;
        int v = min(v0 + row, N - 1);
        const float* xp = C + (size_t)v * 64 + c0;
        float4 f0 = *(const float4*)xp;
        float4 f1 = *(const float4*)(xp + 4);
        float4 f2 = *(const float4*)(xp + 8);
        float4 f3 = *(const float4*)(xp + 12);
        int key = row & 7;
        int s0 = c0 >> 3;
        f16x8 h0, h1;
        h0[0] = (_Float16)f0.x; h0[1] = (_Float16)f0.y;
        h0[2] = (_Float16)f0.z; h0[3] = (_Float16)f0.w;
        h0[4] = (_Float16)f1.x; h0[5] = (_Float16)f1.y;
        h0[6] = (_Float16)f1.z; h0[7] = (_Float16)f1.w;
        h1[0] = (_Float16)f2.x; h1[1] = (_Float16)f2.y;
        h1[2] = (_Float16)f2.z; h1[3] = (_Float16)f2.w;
        h1[4] = (_Float16)f3.x; h1[5] = (_Float16)f3.y;
        h1[6] = (_Float16)f3.z; h1[7] = (_Float16)f3.w;
        *(f16x8*)&lds[row * 64 + ((s0 ^ key) << 3)] = h0;
        *(f16x8*)&lds[row * 64 + (((s0 + 1) ^ key) << 3)] = h1;
    }
    __syncthreads();

    int w = t >> 6, l = t & 63;
    int lr = l & 15, lk = l >> 4;
    int key = lr & 7;
    int arow = w * 16 + lr;
    f16x8 a0 = *(const f16x8*)&lds[arow * 64 + (((0 + lk) ^ key) << 3)];
    f16x8 a1 = *(const f16x8*)&lds[arow * 64 + (((4 + lk) ^ key) << 3)];
    f32x4 acc[6];
#pragma unroll
    for (int i = 0; i < 6; ++i) acc[i] = (f32x4){0.0f, 0.0f, 0.0f, 0.0f};
#pragma unroll
    for (int nt = 0; nt < 6; ++nt) {
        int bc = nt * 16 + lr;
        const unsigned short* wb = &lds[8192 + bc * 64];
        f16x8 b0 = *(const f16x8*)&wb[((0 + lk) ^ key) << 3];
        f16x8 b1v = *(const f16x8*)&wb[((4 + lk) ^ key) << 3];
        acc[nt] = __builtin_amdgcn_mfma_f32_16x16x32_f16(a0, b0, acc[nt], 0, 0, 0);
        acc[nt] = __builtin_amdgcn_mfma_f32_16x16x32_f16(a1, b1v, acc[nt], 0, 0, 0);
    }
    // f32 outputs into C cols 0..63 (in-place; H already staged in LDS)
#pragma unroll
    for (int nt = 0; nt < 4; ++nt) {
        int col = nt * 16 + lr;
#pragma unroll
        for (int r = 0; r < 4; ++r) {
            int v = v0 + w * 16 + lk * 4 + r;
            if (v < N) C[(size_t)v * 64 + col] = acc[nt][r];
        }
    }
    __syncthreads();
    // repack D2 bf16 as [128][32] ushort
#pragma unroll
    for (int nt = 4; nt < 6; ++nt) {
        int col = (nt - 4) * 16 + lr;
#pragma unroll
        for (int r = 0; r < 4; ++r) {
            int vloc = w * 16 + lk * 4 + r;
            lds[vloc * 32 + col] = f2b(acc[nt][r]);
        }
    }
    __syncthreads();
    {
        int i = t;                    // 16B chunk id, 0..511
        int row = i >> 2, ch = i & 3;
        int v = v0 + row;
        if (v < N) {
            uint4 val = *(const uint4*)&lds[i * 8];
            *(uint4*)(B16 + (size_t)v * 32 + ch * 8) = val;
        }
    }
}

// bf16 lane-split gather: NG groups of 64/NG lanes; each lane loads 8 bf16
// (16 B) at src[c*pitch + 8*fl]; xor-reduce over group bits leaves full row
// sums in a[0..7] for all lanes.
template <int NG>
__device__ __forceinline__ void gatherB(const unsigned short* __restrict__ src,
                                        int pitch,
                                        const float* __restrict__ dinv,
                                        const int* __restrict__ sdst,
                                        int beg, int end, int grp, int fl,
                                        float a[8]) {
#pragma unroll
    for (int q = 0; q < 8; ++q) a[q] = 0.0f;
    int e = beg + grp;
    for (; e + NG < end; e += 2 * NG) {
        int c0 = sdst[e];
        int c1 = sdst[e + NG];
        float w0 = dinv[c0], w1 = dinv[c1];
        uint4 r0 = *(const uint4*)(src + (size_t)c0 * pitch + 8 * fl);
        uint4 r1 = *(const uint4*)(src + (size_t)c1 * pitch + 8 * fl);
        a[0] = fmaf(w0, lo16(r0.x), a[0]); a[1] = fmaf(w0, hi16(r0.x), a[1]);
        a[2] = fmaf(w0, lo16(r0.y), a[2]); a[3] = fmaf(w0, hi16(r0.y), a[3]);
        a[4] = fmaf(w0, lo16(r0.z), a[4]); a[5] = fmaf(w0, hi16(r0.z), a[5]);
        a[6] = fmaf(w0, lo16(r0.w), a[6]); a[7] = fmaf(w0, hi16(r0.w), a[7]);
        a[0] = fmaf(w1, lo16(r1.x), a[0]); a[1] = fmaf(w1, hi16(r1.x), a[1]);
        a[2] = fmaf(w1, lo16(r1.y), a[2]); a[3] = fmaf(w1, hi16(r1.y), a[3]);
        a[4] = fmaf(w1, lo16(r1.z), a[4]); a[5] = fmaf(w1, hi16(r1.z), a[5]);
        a[6] = fmaf(w1, lo16(r1.w), a[6]); a[7] = fmaf(w1, hi16(r1.w), a[7]);
    }
    if (e < end) {
        int c = sdst[e];
        float w = dinv[c];
        uint4 r = *(const uint4*)(src + (size_t)c * pitch + 8 * fl);
        a[0] = fmaf(w, lo16(r.x), a[0]); a[1] = fmaf(w, hi16(r.x), a[1]);
        a[2] = fmaf(w, lo16(r.y), a[2]); a[3] = fmaf(w, hi16(r.y), a[3]);
        a[4] = fmaf(w, lo16(r.z), a[4]); a[5] = fmaf(w, hi16(r.z), a[5]);
        a[6] = fmaf(w, lo16(r.w), a[6]); a[7] = fmaf(w, hi16(r.w), a[7]);
    }
#pragma unroll
    for (int m = 64 / NG; m < 64; m <<= 1) {
#pragma unroll
        for (int q = 0; q < 8; ++q) a[q] += __shfl_xor(a[q], m);
    }
}

// Gather 1: B16[v] = bf16( B16[v] - 2*dinv[v]*sum dinv[c]*C16[c] )
__global__ void __launch_bounds__(BLK) k_gath1(const unsigned short* __restrict__ C16,
                                               unsigned short* __restrict__ B16,
                                               const float* __restrict__ dinv,
                                               const int* __restrict__ row_ptr,
                                               const int* __restrict__ sdst,
                                               int N) {
    int v = blockIdx.x * 4 + (threadIdx.x >> 6);
    if (v >= N) return;
    int lane = threadIdx.x & 63;
    int grp = lane >> 3, fl = lane & 7;
    float a[8];
    gatherB<8>(C16, 64, dinv, sdst, row_ptr[v], row_ptr[v + 1], grp, fl, a);
    if (grp == 0) {
        float dv = -2.0f * dinv[v];
        unsigned short* p = B16 + (size_t)v * 64 + 8 * fl;
        uint4 b = *(const uint4*)p;
        float q0 = fmaf(dv, a[0], lo16(b.x)), q1 = fmaf(dv, a[1], hi16(b.x));
        float q2 = fmaf(dv, a[2], lo16(b.y)), q3 = fmaf(dv, a[3], hi16(b.y));
        float q4 = fmaf(dv, a[4], lo16(b.z)), q5 = fmaf(dv, a[5], hi16(b.z));
        float q6 = fmaf(dv, a[6], lo16(b.w)), q7 = fmaf(dv, a[7], hi16(b.w));
        uint4 o;
        o.x = pack2(q0, q1); o.y = pack2(q2, q3);
        o.z = pack2(q4, q5); o.w = pack2(q6, q7);
        *(uint4*)p = o;
    }
}

// Gather 2: C[v] (f32 H) = dropout(relu(D[v] + S(B16)[v])).
// Dropout-word shuffles executed by ALL lanes.
__global__ void __launch_bounds__(BLK) k_gath2(const float* __restrict__ D,
                                               const unsigned short* __restrict__ B16,
                                               float* __restrict__ C,
                                               const float* __restrict__ dinv,
                                               const int* __restrict__ row_ptr,
                                               const int* __restrict__ sdst,
                                               int N) {
    int v = blockIdx.x * 4 + (threadIdx.x >> 6);
    if (v >= N) return;
    int lane = threadIdx.x & 63;
    int grp = lane >> 3, fl = lane & 7;
    float a[8];
    gatherB<8>(B16, 64, dinv, sdst, row_ptr[v], row_ptr[v + 1], grp, fl, a);
    unsigned w = tf_word((unsigned)v * 64u + (unsigned)lane);
    unsigned ww[8];
#pragma unroll
    for (int k = 0; k < 8; ++k) ww[k] = __shfl(w, 8 * fl + k);
    if (grp == 0) {
        float dv = -dinv[v];
        const float* dp = D + (size_t)v * 64 + 8 * fl;
        float4 dA = *(const float4*)dp;
        float4 dB = *(const float4*)(dp + 4);
        float o[8];
        o[0] = fmaxf(fmaf(dv, a[0], dA.x), 0.0f);
        o[1] = fmaxf(fmaf(dv, a[1], dA.y), 0.0f);
        o[2] = fmaxf(fmaf(dv, a[2], dA.z), 0.0f);
        o[3] = fmaxf(fmaf(dv, a[3], dA.w), 0.0f);
        o[4] = fmaxf(fmaf(dv, a[4], dB.x), 0.0f);
        o[5] = fmaxf(fmaf(dv, a[5], dB.y), 0.0f);
        o[6] = fmaxf(fmaf(dv, a[6], dB.z), 0.0f);
        o[7] = fmaxf(fmaf(dv, a[7], dB.w), 0.0f);
#pragma unroll
        for (int k = 0; k < 8; ++k)
            o[k] = (ww[k] & 0x80000000u) ? 0.0f : o[k] * 2.0f;
        float* cp = C + (size_t)v * 64 + 8 * fl;
        *(float4*)cp = make_float4(o[0], o[1], o[2], o[3]);
        *(float4*)(cp + 4) = make_float4(o[4], o[5], o[6], o[7]);
    }
}

// Gather 3: R16[v] = bf16( D1[v] - 2*dinv[v]*sum dinv[c]*D2[c] ), D2 in B16 pitch 32.
__global__ void __launch_bounds__(BLK) k_gath3(const unsigned short* __restrict__ B16,
                                               const float* __restrict__ C,
                                               unsigned short* __restrict__ R16,
                                               const float* __restrict__ dinv,
                                               const int* __restrict__ row_ptr,
                                               const int* __restrict__ sdst,
                                               int N) {
    int v = blockIdx.x * 4 + (threadIdx.x >> 6);
    if (v >= N) return;
    int lane = threadIdx.x & 63;
    int grp = lane >> 2, fl = lane & 3;
    float a[8];
    gatherB<16>(B16, 32, dinv, sdst, row_ptr[v], row_ptr[v + 1], grp, fl, a);
    if (grp == 0) {
        float dv = -2.0f * dinv[v];
        const float* dp = C + (size_t)v * 64 + 32 + 8 * fl;
        float4 dA = *(const float4*)dp;
        float4 dB = *(const float4*)(dp + 4);
        uint4 o;
        o.x = pack2(fmaf(dv, a[0], dA.x), fmaf(dv, a[1], dA.y));
        o.y = pack2(fmaf(dv, a[2], dA.z), fmaf(dv, a[3], dA.w));
        o.z = pack2(fmaf(dv, a[4], dB.x), fmaf(dv, a[5], dB.y));
        o.w = pack2(fmaf(dv, a[6], dB.z), fmaf(dv, a[7], dB.w));
        *(uint4*)(R16 + (size_t)v * 32 + 8 * fl) = o;
    }
}

// Gather 4: out = log_softmax(D0 + b2 + S(R16)).
__global__ void __launch_bounds__(BLK) k_gath4(const unsigned short* __restrict__ R16,
                                               const float* __restrict__ C,
                                               const float* __restrict__ dinv,
                                               const int* __restrict__ row_ptr,
                                               const int* __restrict__ sdst,
                                               const float* __restrict__ b2,
                                               int N, float* __restrict__ out) {
    int v = blockIdx.x * 4 + (threadIdx.x >> 6);
    if (v >= N) return;
    int lane = threadIdx.x & 63;
    int grp = lane >> 2, fl = lane & 3;
    float a[8];
    gatherB<16>(R16, 32, dinv, sdst, row_ptr[v], row_ptr[v + 1], grp, fl, a);
    float dv = -dinv[v];
    const float* dp = C + (size_t)v * 64 + 8 * fl;
    float4 dA = *(const float4*)dp;
    float4 dB = *(const float4*)(dp + 4);
    const float* bp = b2 + 8 * fl;
    float4 bA = *(const float4*)bp;
    float4 bB = *(const float4*)(bp + 4);
    float o[8];
    o[0] = fmaf(dv, a[0], dA.x + bA.x);
    o[1] = fmaf(dv, a[1], dA.y + bA.y);
    o[2] = fmaf(dv, a[2], dA.z + bA.z);
    o[3] = fmaf(dv, a[3], dA.w + bA.w);
    o[4] = fmaf(dv, a[4], dB.x + bB.x);
    o[5] = fmaf(dv, a[5], dB.y + bB.y);
    o[6] = fmaf(dv, a[6], dB.z + bB.z);
    o[7] = fmaf(dv, a[7], dB.w + bB.w);
    float m = o[0];
#pragma unroll
    for (int k = 1; k < 8; ++k) m = fmaxf(m, o[k]);
    m = fmaxf(m, __shfl_xor(m, 1));
    m = fmaxf(m, __shfl_xor(m, 2));
    float s = 0.0f;
#pragma unroll
    for (int k = 0; k < 8; ++k) s += expf(o[k] - m);
    s += __shfl_xor(s, 1);
    s += __shfl_xor(s, 2);
    float lse = m + logf(s);
    if (grp == 0) {
        float* op = out + (size_t)v * 32 + 8 * fl;
        *(float4*)op = make_float4(o[0] - lse, o[1] - lse, o[2] - lse, o[3] - lse);
        *(float4*)(op + 4) = make_float4(o[4] - lse, o[5] - lse, o[6] - lse, o[7] - lse);
    }
}

extern "C" void kernel_launch(void* const* d_in, const int* in_sizes, int n_in,
                              void* d_out, int out_size, void* d_ws, size_t ws_size,
                              hipStream_t stream) {
    const float* x  = (const float*)d_in[0];
    const int* ei   = (const int*)d_in[1];
    const float* W1 = (const float*)d_in[2];
    const float* b1 = (const float*)d_in[3];
    const float* W2 = (const float*)d_in[4];
    const float* b2 = (const float*)d_in[5];
    float* out = (float*)d_out;

    const int N = in_sizes[0] / 64;
    const int E = in_sizes[1] / 2;
    const int NB = (N + ROWB - 1) >> RB_SHIFT;

    char* ws = (char*)d_ws;
    size_t off = 0;
    auto alloc = [&](size_t bytes) -> void* {
        void* p = ws + off;
        off = (off + bytes + 511) & ~(size_t)511;
        return p;
    };
    int*      flags   = (int*)alloc(16);
    int*      deg     = (int*)alloc((size_t)N * 4);
    float*    dinv    = (float*)alloc((size_t)N * 4);
    int*      row_ptr = (int*)alloc(((size_t)N + 1) * 4);
    int*      blk_sum = (int*)alloc(4096);
    int*      bcnt    = (int*)alloc((size_t)NB * 4);
    // D (f32 N*64, 25.6 MB) aliases bdata (9.6 MB, dead after k_place).
    size_t dbytes = (size_t)N * 64 * 4;
    size_t bdbytes = (size_t)NB * BCAP * 4;
    unsigned* bdata = (unsigned*)alloc(dbytes > bdbytes ? dbytes : bdbytes);
    float*    D     = (float*)bdata;
    int*      sdst  = (int*)alloc((size_t)E * 4);
    float*    C     = (float*)alloc((size_t)N * 64 * 4);
    unsigned short* B16 = (unsigned short*)alloc((size_t)N * 64 * 2);
    // C16 (layer-1 gather source, dead after gath1) shares with R16 (layer-2).
    unsigned short* C16 = (unsigned short*)alloc((size_t)N * 64 * 2);
    unsigned short* R16 = C16;
    unsigned short* wt1 = (unsigned short*)alloc(12288 * 2);
    unsigned short* wt2 = (unsigned short*)alloc(6144 * 2);
    // total ~84 MB

    hipMemsetAsync(bcnt, 0, (size_t)NB * 4, stream);

    const int gN = (N + BLK - 1) / BLK;
    const int gW4 = (N + 3) / 4;
    const int gDM = (N + 127) / 128;
    const int nb = (N + SCAN_CHUNK - 1) / SCAN_CHUNK;
    const int gBin = (E + CHUNK - 1) / CHUNK;

    k_wprep<<<72, 256, 0, stream>>>(W1, W2, wt1, wt2);
    k_detect<<<1, 256, 0, stream>>>(ei, flags);
    k_bin<<<gBin, 256, 0, stream>>>(ei, E, flags, bcnt, bdata, NB);
    k_hist2<<<NB, 256, 0, stream>>>(bdata, bcnt, N, deg);
    k_dinv<<<gN, BLK, 0, stream>>>(deg, N, dinv);
    k_scanA<<<nb, SCAN_CHUNK, 0, stream>>>(deg, N, blk_sum);
    k_scanB<<<1, 1024, 0, stream>>>(blk_sum, nb);
    k_scanC<<<nb, SCAN_CHUNK, 0, stream>>>(deg, N, E, blk_sum, row_ptr);
    k_place<<<NB, 256, 0, stream>>>(bdata, bcnt, row_ptr, N, sdst);

    // Layer 1: B16=bf16(x@W1[1]), C16=bf16(x@W1[2]), D=x@(W1[0]-W1[2])+b1;
    // B16 += 2*S(C16); C = drop(relu(D + S(B16)))
    k_dense3<<<gDM, 512, 0, stream>>>(x, wt1, b1, N, B16, C16, D);
    k_gath1<<<gW4, BLK, 0, stream>>>(C16, B16, dinv, row_ptr, sdst, N);
    k_gath2<<<gW4, BLK, 0, stream>>>(D, B16, C, dinv, row_ptr, sdst, N);

    // Layer 2: D0,D1 f32 in C; D2 bf16 in B16 (pitch 32);
    // R16 = bf16(D1 + 2*S(D2)); out = lsm(D0 + b2 + S(R16))
    k_dense3b<<<gDM, 512, 0, stream>>>(wt2, N, B16, C);
    k_gath3<<<gW4, BLK, 0, stream>>>(B16, C, R16, dinv, row_ptr, sdst, N);
    k_gath4<<<gW4, BLK, 0, stream>>>(R16, C, dinv, row_ptr, sdst, b2, N, out);
}

// Round 2
// 282.687 us; speedup vs baseline: 1.3889x; 1.2004x over previous
//
#include <hip/hip_runtime.h>

// ChebNet K=3, W-first form: ChebConv(H) = H@(W0-W2) + S·(H@W1 + 2·S·(H@W2)).
// Round 15: gather kernels restructured to 2 nodes/wave (half-wave per node),
// gather sources pre-scaled by dinv[c] at the producer (no per-edge dinv
// loads), D0/D1 compacted to pitch-32 f32 buffers (full-line fetches),
// __expf/__logf in the softmax, k_dinv fused into k_hist2.

static constexpr int BLK = 256;
static constexpr int SCAN_CHUNK = 256;
static constexpr int ROWB = 256;
static constexpr int RB_SHIFT = 8;
static constexpr int BCAP = 6144;
static constexpr int CHUNK = 8192;

typedef _Float16 f16x8 __attribute__((ext_vector_type(8)));
typedef float f32x4 __attribute__((ext_vector_type(4)));

__device__ __forceinline__ unsigned rotl32(unsigned x, int r) {
    return (x << r) | (x >> (32 - r));
}

// JAX partitionable threefry word for element i:
// (b1,b2) = threefry2x32(key=(0,42), counter=(0,i)); word = b1 ^ b2.
__device__ __forceinline__ unsigned tf_word(unsigned i) {
    const unsigned ks0 = 0u;
    const unsigned ks1 = 42u;
    const unsigned ks2 = 0u ^ 42u ^ 0x1BD11BDAu;
    unsigned x0 = 0u + ks0;
    unsigned x1 = i + ks1;
#define TF_RND(r) { x0 += x1; x1 = rotl32(x1, (r)); x1 ^= x0; }
    TF_RND(13) TF_RND(15) TF_RND(26) TF_RND(6)
    x0 += ks1; x1 += ks2 + 1u;
    TF_RND(17) TF_RND(29) TF_RND(16) TF_RND(24)
    x0 += ks2; x1 += ks0 + 2u;
    TF_RND(13) TF_RND(15) TF_RND(26) TF_RND(6)
    x0 += ks0; x1 += ks1 + 3u;
    TF_RND(17) TF_RND(29) TF_RND(16) TF_RND(24)
    x0 += ks1; x1 += ks2 + 4u;
    TF_RND(13) TF_RND(15) TF_RND(26) TF_RND(6)
    x0 += ks2; x1 += ks0 + 5u;
#undef TF_RND
    return x0 ^ x1;
}

// bf16 pack/unpack
__device__ __forceinline__ float lo16(unsigned u) {
    union { unsigned x; float f; } c; c.x = u << 16; return c.f;
}
__device__ __forceinline__ float hi16(unsigned u) {
    union { unsigned x; float f; } c; c.x = u & 0xFFFF0000u; return c.f;
}
__device__ __forceinline__ unsigned short f2b(float f) {
    union { float f; unsigned u; } c; c.f = f;
    unsigned r = (c.u + 0x7FFFu + ((c.u >> 16) & 1u)) >> 16;
    return (unsigned short)r;
}
__device__ __forceinline__ unsigned pack2(float a, float b) {
    return (unsigned)f2b(a) | ((unsigned)f2b(b) << 16);
}

__global__ void k_detect(const int* __restrict__ ei, int* __restrict__ flags) {
    __shared__ int cnt_nz;
    int t = threadIdx.x;
    if (t == 0) cnt_nz = 0;
    __syncthreads();
    if (ei[2 * t + 1] != 0) atomicAdd(&cnt_nz, 1);
    __syncthreads();
    if (t == 0) flags[0] = (cnt_nz == 0) ? 1 : 0;
}

// Pass 1: bin edges into row-buckets, LDS-staged for coalesced writes.
__global__ void __launch_bounds__(256) k_bin(const int* __restrict__ ei, int E,
                                             const int* __restrict__ flags,
                                             int* __restrict__ bcnt,
                                             unsigned* __restrict__ bdata, int NB) {
    __shared__ unsigned sval[CHUNK];
    __shared__ unsigned short sbkt[CHUNK];
    __shared__ int h[512], ex[512], cur[512], basep[512];
    int t = threadIdx.x;
    int start = blockIdx.x * CHUNK;
    int lim = min(CHUNK, E - start);
    bool i64 = flags[0] != 0;
    h[t] = 0; h[t + 256] = 0;
    __syncthreads();
    unsigned vv[32];
    unsigned short bb_[32];
#pragma unroll
    for (int k = 0; k < 32; ++k) {
        int idx = k * 256 + t;
        int e = start + idx;
        if (idx < lim) {
            int r, c;
            if (i64) { r = ei[2 * e]; c = ei[2 * (E + e)]; }
            else     { r = ei[e];     c = ei[E + e]; }
            int b = r >> RB_SHIFT;
            vv[k] = ((unsigned)(r & (ROWB - 1)) << 17) | (unsigned)c;
            bb_[k] = (unsigned short)b;
            atomicAdd(&h[b], 1);
        } else {
            bb_[k] = 0xFFFF;
        }
    }
    __syncthreads();
    int i0 = t, i1 = t + 256;
    ex[i0] = h[i0]; ex[i1] = h[i1];
    __syncthreads();
    for (int off = 1; off < 512; off <<= 1) {
        int v0 = (i0 >= off) ? ex[i0 - off] : 0;
        int v1 = (i1 >= off) ? ex[i1 - off] : 0;
        __syncthreads();
        ex[i0] += v0; ex[i1] += v1;
        __syncthreads();
    }
    int e0 = ex[i0] - h[i0], e1 = ex[i1] - h[i1];
    __syncthreads();
    ex[i0] = e0; cur[i0] = e0;
    ex[i1] = e1; cur[i1] = e1;
    if (i0 < NB && h[i0] > 0) basep[i0] = atomicAdd(&bcnt[i0], h[i0]);
    if (i1 < NB && h[i1] > 0) basep[i1] = atomicAdd(&bcnt[i1], h[i1]);
    __syncthreads();
#pragma unroll
    for (int k = 0; k < 32; ++k) {
        if (bb_[k] != 0xFFFF) {
            int p = atomicAdd(&cur[bb_[k]], 1);
            sval[p] = vv[k];
            sbkt[p] = bb_[k];
        }
    }
    __syncthreads();
    for (int i = t; i < lim; i += 256) {
        int b = sbkt[i];
        int gpos = basep[b] + (i - ex[b]);
        if (gpos < BCAP) bdata[(size_t)b * BCAP + gpos] = sval[i];
    }
}

// hist + dinv fused
__global__ void __launch_bounds__(256) k_hist2(const unsigned* __restrict__ bdata,
                                               const int* __restrict__ bcnt,
                                               int N, int* __restrict__ deg,
                                               float* __restrict__ dinv) {
    __shared__ int h[ROWB];
    int t = threadIdx.x, b = blockIdx.x;
    h[t] = 0;
    __syncthreads();
    int cnt = min(bcnt[b], BCAP);
    for (int i = t; i < cnt; i += 256)
        atomicAdd(&h[bdata[(size_t)b * BCAP + i] >> 17], 1);
    __syncthreads();
    int r = b * ROWB + t;
    if (r < N) {
        int d = h[t];
        deg[r] = d;
        dinv[r] = (d > 0) ? rsqrtf((float)d) : 0.0f;
    }
}

__global__ void k_scanA(const int* __restrict__ deg, int N, int* __restrict__ blk_sum) {
    __shared__ int lds[SCAN_CHUNK];
    int i = blockIdx.x * SCAN_CHUNK + threadIdx.x;
    int v = (i < N) ? deg[i] : 0;
    lds[threadIdx.x] = v;
    __syncthreads();
    for (int off = SCAN_CHUNK / 2; off > 0; off >>= 1) {
        if (threadIdx.x < off) lds[threadIdx.x] += lds[threadIdx.x + off];
        __syncthreads();
    }
    if (threadIdx.x == 0) blk_sum[blockIdx.x] = lds[0];
}

__global__ void k_scanB(int* __restrict__ blk_sum, int nb) {
    __shared__ int lds[1024];
    int t = threadIdx.x;
    int v = (t < nb) ? blk_sum[t] : 0;
    lds[t] = v;
    __syncthreads();
    for (int off = 1; off < 1024; off <<= 1) {
        int val = (t >= off) ? lds[t - off] : 0;
        __syncthreads();
        lds[t] += val;
        __syncthreads();
    }
    if (t < nb) blk_sum[t] = lds[t] - v;
}

__global__ void k_scanC(const int* __restrict__ deg, int N, int E,
                        const int* __restrict__ blk_sum, int* __restrict__ row_ptr) {
    __shared__ int lds[SCAN_CHUNK];
    int t = threadIdx.x;
    int i = blockIdx.x * SCAN_CHUNK + t;
    int v = (i < N) ? deg[i] : 0;
    lds[t] = v;
    __syncthreads();
    for (int off = 1; off < SCAN_CHUNK; off <<= 1) {
        int val = (t >= off) ? lds[t - off] : 0;
        __syncthreads();
        lds[t] += val;
        __syncthreads();
    }
    if (i < N) row_ptr[i] = blk_sum[blockIdx.x] + lds[t] - v;
    if (blockIdx.x == gridDim.x - 1 && t == SCAN_CHUNK - 1) row_ptr[N] = E;
}

__global__ void __launch_bounds__(256) k_place(const unsigned* __restrict__ bdata,
                                               const int* __restrict__ bcnt,
                                               const int* __restrict__ row_ptr,
                                               int N, int* __restrict__ sdst) {
    __shared__ int cur[ROWB];
    __shared__ int staged[BCAP];
    int t = threadIdx.x, b = blockIdx.x;
    int r0 = b * ROWB;
    int rbase = row_ptr[r0];
    int r = r0 + t;
    cur[t] = (r < N) ? (row_ptr[r] - rbase) : 0;
    __syncthreads();
    int cnt = min(bcnt[b], BCAP);
    for (int i = t; i < cnt; i += 256) {
        unsigned val = bdata[(size_t)b * BCAP + i];
        int p = atomicAdd(&cur[val >> 17], 1);
        staged[p] = (int)(val & 0x1FFFFu);
    }
    __syncthreads();
    for (int i = t; i < cnt; i += 256) sdst[rbase + i] = staged[i];
}

// Weight prep: fp16, transposed (col-major over output col), pre-XOR-swizzled
// LDS image. wt1: 192 cols x 64 k = [Wd=W1[0]-W1[2] | W1[1] | W1[2]].
// wt2: 96 cols x 64 k = [Wd2=W2[0]-W2[2] | W2[1] | W2[2]].
__global__ void k_wprep(const float* __restrict__ W1, const float* __restrict__ W2,
                        unsigned short* __restrict__ wt1,
                        unsigned short* __restrict__ wt2) {
    int idx = blockIdx.x * 256 + threadIdx.x;
    if (idx < 12288) {
        int c = idx >> 6, r6 = idx & 63;
        int slot = (r6 >> 3) ^ (c & 7);
        int k = slot * 8 + (r6 & 7);
        float v;
        if (c < 64)       v = W1[k * 64 + c] - W1[8192 + k * 64 + c];
        else if (c < 128) v = W1[4096 + k * 64 + (c - 64)];
        else              v = W1[8192 + k * 64 + (c - 128)];
        union { _Float16 h; unsigned short u; } cv; cv.h = (_Float16)v;
        wt1[idx] = cv.u;
    } else {
        int j = idx - 12288;
        int c = j >> 6, r6 = j & 63;
        int slot = (r6 >> 3) ^ (c & 7);
        int k = slot * 8 + (r6 & 7);
        float v;
        if (c < 32)      v = W2[k * 32 + c] - W2[4096 + k * 32 + c];
        else if (c < 64) v = W2[2048 + k * 32 + (c - 32)];
        else             v = W2[4096 + k * 32 + (c - 64)];
        union { _Float16 h; unsigned short u; } cv; cv.h = (_Float16)v;
        wt2[j] = cv.u;
    }
}

// MFMA dense, layer 1. 128 nodes/block, 512 threads = 8 waves, each wave owns
// one 16-row M-tile x 12 N-tiles (192 cols = D | B16 | C16), K=64 in 2 steps
// of v_mfma_f32_16x16x32_f16. C16 is pre-scaled by dinv[v] (gather weights
// folded into the stored rows).
__global__ void __launch_bounds__(512) k_dense3(const float* __restrict__ x,
                                                const unsigned short* __restrict__ wt1,
                                                const float* __restrict__ b1,
                                                const float* __restrict__ dinv,
                                                int N,
                                                unsigned short* __restrict__ B16,
                                                unsigned short* __restrict__ C16,
                                                float* __restrict__ D) {
    __shared__ unsigned short lds[20480] __attribute__((aligned(16)));  // x:[0,8192) W:[8192,20480)
    __shared__ float sb[64];
    int t = threadIdx.x;
    int v0 = blockIdx.x * 128;
    {
        const uint4* src = (const uint4*)wt1;
        uint4* dst = (uint4*)&lds[8192];
        for (int i = t; i < 1536; i += 512) dst[i] = src[i];
    }
    if (t < 64) sb[t] = b1[t];
    {
        int row = t >> 2, c0 = (t & 3) << 4;
        int v = min(v0 + row, N - 1);
        const float* xp = x + (size_t)v * 64 + c0;
        float4 f0 = *(const float4*)xp;
        float4 f1 = *(const float4*)(xp + 4);
        float4 f2 = *(const float4*)(xp + 8);
        float4 f3 = *(const float4*)(xp + 12);
        int key = row & 7;
        int s0 = c0 >> 3;
        f16x8 h0, h1;
        h0[0] = (_Float16)f0.x; h0[1] = (_Float16)f0.y;
        h0[2] = (_Float16)f0.z; h0[3] = (_Float16)f0.w;
        h0[4] = (_Float16)f1.x; h0[5] = (_Float16)f1.y;
        h0[6] = (_Float16)f1.z; h0[7] = (_Float16)f1.w;
        h1[0] = (_Float16)f2.x; h1[1] = (_Float16)f2.y;
        h1[2] = (_Float16)f2.z; h1[3] = (_Float16)f2.w;
        h1[4] = (_Float16)f3.x; h1[5] = (_Float16)f3.y;
        h1[6] = (_Float16)f3.z; h1[7] = (_Float16)f3.w;
        *(f16x8*)&lds[row * 64 + ((s0 ^ key) << 3)] = h0;
        *(f16x8*)&lds[row * 64 + (((s0 + 1) ^ key) << 3)] = h1;
    }
    __syncthreads();

    int w = t >> 6, l = t & 63;
    int lr = l & 15, lk = l >> 4;
    int key = lr & 7;
    int arow = w * 16 + lr;
    f16x8 a0 = *(const f16x8*)&lds[arow * 64 + (((0 + lk) ^ key) << 3)];
    f16x8 a1 = *(const f16x8*)&lds[arow * 64 + (((4 + lk) ^ key) << 3)];
    f32x4 acc[12];
#pragma unroll
    for (int i = 0; i < 12; ++i) acc[i] = (f32x4){0.0f, 0.0f, 0.0f, 0.0f};
#pragma unroll
    for (int nt = 0; nt < 12; ++nt) {
        int bc = nt * 16 + lr;
        const unsigned short* wb = &lds[8192 + bc * 64];
        f16x8 b0 = *(const f16x8*)&wb[((0 + lk) ^ key) << 3];
        f16x8 b1v = *(const f16x8*)&wb[((4 + lk) ^ key) << 3];
        acc[nt] = __builtin_amdgcn_mfma_f32_16x16x32_f16(a0, b0, acc[nt], 0, 0, 0);
        acc[nt] = __builtin_amdgcn_mfma_f32_16x16x32_f16(a1, b1v, acc[nt], 0, 0, 0);
    }
    // dinv for this lane's 4 accumulator rows (contiguous, 16B-aligned)
    float4 dv4 = *(const float4*)&dinv[v0 + w * 16 + lk * 4];
    float dsc[4] = {dv4.x, dv4.y, dv4.z, dv4.w};
    // D (f32, cols 0..63) + b1, direct stores
#pragma unroll
    for (int nt = 0; nt < 4; ++nt) {
        int col = nt * 16 + lr;
        float bv = sb[col];
#pragma unroll
        for (int r = 0; r < 4; ++r) {
            int v = v0 + w * 16 + lk * 4 + r;
            if (v < N) D[(size_t)v * 64 + col] = acc[nt][r] + bv;
        }
    }
    __syncthreads();
    // repack bf16 outputs (B16 unscaled || C16 pre-scaled) as [128][128] ushort
#pragma unroll
    for (int nt = 4; nt < 8; ++nt) {
        int col = (nt - 4) * 16 + lr;
#pragma unroll
        for (int r = 0; r < 4; ++r) {
            int vloc = w * 16 + lk * 4 + r;
            lds[vloc * 128 + col] = f2b(acc[nt][r]);
        }
    }
#pragma unroll
    for (int nt = 8; nt < 12; ++nt) {
        int col = (nt - 4) * 16 + lr;
#pragma unroll
        for (int r = 0; r < 4; ++r) {
            int vloc = w * 16 + lk * 4 + r;
            lds[vloc * 128 + col] = f2b(acc[nt][r] * dsc[r]);
        }
    }
    __syncthreads();
#pragma unroll
    for (int q = 0; q < 4; ++q) {
        int i = q * 512 + t;
        int row = i >> 4, ch = i & 15;
        int v = v0 + row;
        if (v < N) {
            uint4 val = *(const uint4*)&lds[i * 8];
            unsigned short* dst = (ch < 8)
                ? (B16 + (size_t)v * 64 + ch * 8)
                : (C16 + (size_t)v * 64 + (ch - 8) * 8);
            *(uint4*)dst = val;
        }
    }
}

// MFMA dense, layer 2. 128 nodes/block, 512 threads. 96 output cols:
// nt0,1 -> P0 (f32 pitch 32, D0=H@(W2[0]-W2[2])); nt2,3 -> P1 (D1=H@W2[1]);
// nt4,5 -> D2=H@W2[2] pre-scaled by dinv, bf16 into B16 pitch 32.
__global__ void __launch_bounds__(512) k_dense3b(const unsigned short* __restrict__ wt2,
                                                 const float* __restrict__ dinv,
                                                 int N,
                                                 unsigned short* __restrict__ B16,
                                                 const float* __restrict__ C,
                                                 float* __restrict__ P0,
                                                 float* __restrict__ P1) {
    __shared__ unsigned short lds[14336] __attribute__((aligned(16)));  // x:[0,8192) W:[8192,14336)
    int t = threadIdx.x;
    int v0 = blockIdx.x * 128;
    {
        const uint4* src = (const uint4*)wt2;
        uint4* dst = (uint4*)&lds[8192];
        for (int i = t; i < 768; i += 512) dst[i] = src[i];
    }
    {
        int row = t >> 2, c0 = (t & 3) << 4;
        int v = min(v0 + row, N - 1);
        const float* xp = C + (size_t)v * 64 + c0;
        float4 f0 = *(const float4*)xp;
        float4 f1 = *(const float4*)(xp + 4);
        float4 f2 = *(const float4*)(xp + 8);
        float4 f3 = *(const float4*)(xp + 12);
        int key = row & 7;
        int s0 = c0 >> 3;
        f16x8 h0, h1;
        h0[0] = (_Float16)f0.x; h0[1] = (_Float16)f0.y;
        h0[2] = (_Float16)f0.z; h0[3] = (_Float16)f0.w;
        h0[4] = (_Float16)f1.x; h0[5] = (_Float16)f1.y;
        h0[6] = (_Float16)f1.z; h0[7] = (_Float16)f1.w;
        h1[0] = (_Float16)f2.x; h1[1] = (_Float16)f2.y;
        h1[2] = (_Float16)f2.z; h1[3] = (_Float16)f2.w;
        h1[4] = (_Float16)f3.x; h1[5] = (_Float16)f3.y;
        h1[6] = (_Float16)f3.z; h1[7] = (_Float16)f3.w;
        *(f16x8*)&lds[row * 64 + ((s0 ^ key) << 3)] = h0;
        *(f16x8*)&lds[row * 64 + (((s0 + 1) ^ key) << 3)] = h1;
    }
    __syncthreads();

    int w = t >> 6, l = t & 63;
    int lr = l & 15, lk = l >> 4;
    int key = lr & 7;
    int arow = w * 16 + lr;
    f16x8 a0 = *(const f16x8*)&lds[arow * 64 + (((0 + lk) ^ key) << 3)];
    f16x8 a1 = *(const f16x8*)&lds[arow * 64 + (((4 + lk) ^ key) << 3)];
    f32x4 acc[6];
#pragma unroll
    for (int i = 0; i < 6; ++i) acc[i] = (f32x4){0.0f, 0.0f, 0.0f, 0.0f};
#pragma unroll
    for (int nt = 0; nt < 6; ++nt) {
        int bc = nt * 16 + lr;
        const unsigned short* wb = &lds[8192 + bc * 64];
        f16x8 b0 = *(const f16x8*)&wb[((0 + lk) ^ key) << 3];
        f16x8 b1v = *(const f16x8*)&wb[((4 + lk) ^ key) << 3];
        acc[nt] = __builtin_amdgcn_mfma_f32_16x16x32_f16(a0, b0, acc[nt], 0, 0, 0);
        acc[nt] = __builtin_amdgcn_mfma_f32_16x16x32_f16(a1, b1v, acc[nt], 0, 0, 0);
    }
    float4 dv4 = *(const float4*)&dinv[v0 + w * 16 + lk * 4];
    float dsc[4] = {dv4.x, dv4.y, dv4.z, dv4.w};
    // f32 outputs: nt0,1 -> P0; nt2,3 -> P1 (both pitch 32)
#pragma unroll
    for (int nt = 0; nt < 4; ++nt) {
        int col = (nt & 1) * 16 + lr;
        float* dst = (nt < 2) ? P0 : P1;
#pragma unroll
        for (int r = 0; r < 4; ++r) {
            int v = v0 + w * 16 + lk * 4 + r;
            if (v < N) dst[(size_t)v * 32 + col] = acc[nt][r];
        }
    }
    __syncthreads();
    // repack D2 (pre-scaled) bf16 as [128][32] ushort
#pragma unroll
    for (int nt = 4; nt < 6; ++nt) {
        int col = (nt - 4) * 16 + lr;
#pragma unroll
        for (int r = 0; r < 4; ++r) {
            int vloc = w * 16 + lk * 4 + r;
            lds[vloc * 32 + col] = f2b(acc[nt][r] * dsc[r]);
        }
    }
    __syncthreads();
    {
        int i = t;
        int row = i >> 2, ch = i & 3;
        int v = v0 + row;
        if (v < N) {
            uint4 val = *(const uint4*)&lds[i * 8];
            *(uint4*)(B16 + (size_t)v * 32 + ch * 8) = val;
        }
    }
}

// Half-wave gather: 32 lanes per node. Sources pre-scaled by dinv[c], so the
// inner loop is pure bf16-unpack + add. NG = 32/(PITCH/8) groups; xor-reduce
// over group bits (all masks < 32 -> stays within the half-wave).
template <int PITCH>
__device__ __forceinline__ void gatherH(const unsigned short* __restrict__ src,
                                        const int* __restrict__ sdst,
                                        int beg, int end, int grp, int fl,
                                        float a[8]) {
    constexpr int NG = 32 / (PITCH / 8);
#pragma unroll
    for (int q = 0; q < 8; ++q) a[q] = 0.0f;
    int e = beg + grp;
    for (; e + NG < end; e += 2 * NG) {
        int c0 = sdst[e];
        int c1 = sdst[e + NG];
        uint4 r0 = *(const uint4*)(src + (size_t)c0 * PITCH + 8 * fl);
        uint4 r1 = *(const uint4*)(src + (size_t)c1 * PITCH + 8 * fl);
        a[0] += lo16(r0.x); a[1] += hi16(r0.x);
        a[2] += lo16(r0.y); a[3] += hi16(r0.y);
        a[4] += lo16(r0.z); a[5] += hi16(r0.z);
        a[6] += lo16(r0.w); a[7] += hi16(r0.w);
        a[0] += lo16(r1.x); a[1] += hi16(r1.x);
        a[2] += lo16(r1.y); a[3] += hi16(r1.y);
        a[4] += lo16(r1.z); a[5] += hi16(r1.z);
        a[6] += lo16(r1.w); a[7] += hi16(r1.w);
    }
    if (e < end) {
        int c = sdst[e];
        uint4 r = *(const uint4*)(src + (size_t)c * PITCH + 8 * fl);
        a[0] += lo16(r.x); a[1] += hi16(r.x);
        a[2] += lo16(r.y); a[3] += hi16(r.y);
        a[4] += lo16(r.z); a[5] += hi16(r.z);
        a[6] += lo16(r.w); a[7] += hi16(r.w);
    }
#pragma unroll
    for (int m = PITCH / 8; m < 32; m <<= 1) {
#pragma unroll
        for (int q = 0; q < 8; ++q) a[q] += __shfl_xor(a[q], m);
    }
}

// Gather 1: B16[v] = bf16( dinv[v] * (B16[v] - 2*dinv[v]*sum C16'[c]) )
// (output pre-scaled for gather 2)
__global__ void __launch_bounds__(BLK) k_gath1(const unsigned short* __restrict__ C16,
                                               unsigned short* __restrict__ B16,
                                               const float* __restrict__ dinv,
                                               const int* __restrict__ row_ptr,
                                               const int* __restrict__ sdst,
                                               int N) {
    int v = blockIdx.x * 8 + (threadIdx.x >> 5);
    if (v >= N) return;
    int hl = threadIdx.x & 31;
    int grp = hl >> 3, fl = hl & 7;
    float a[8];
    gatherH<64>(C16, sdst, row_ptr[v], row_ptr[v + 1], grp, fl, a);
    if (grp == 0) {
        float di = dinv[v];
        float dv = -2.0f * di;
        unsigned short* p = B16 + (size_t)v * 64 + 8 * fl;
        uint4 b = *(const uint4*)p;
        float q0 = di * fmaf(dv, a[0], lo16(b.x)), q1 = di * fmaf(dv, a[1], hi16(b.x));
        float q2 = di * fmaf(dv, a[2], lo16(b.y)), q3 = di * fmaf(dv, a[3], hi16(b.y));
        float q4 = di * fmaf(dv, a[4], lo16(b.z)), q5 = di * fmaf(dv, a[5], hi16(b.z));
        float q6 = di * fmaf(dv, a[6], lo16(b.w)), q7 = di * fmaf(dv, a[7], hi16(b.w));
        uint4 o;
        o.x = pack2(q0, q1); o.y = pack2(q2, q3);
        o.z = pack2(q4, q5); o.w = pack2(q6, q7);
        *(uint4*)p = o;
    }
}

// Gather 2: C[v] (f32 H) = dropout(relu(D[v] - dinv[v]*sum B16'[c])).
// Dropout words: each lane makes 2 (features 2*hl, 2*hl+1), shuffled to writers.
__global__ void __launch_bounds__(BLK) k_gath2(const float* __restrict__ D,
                                               const unsigned short* __restrict__ B16,
                                               float* __restrict__ C,
                                               const float* __restrict__ dinv,
                                               const int* __restrict__ row_ptr,
                                               const int* __restrict__ sdst,
                                               int N) {
    int v = blockIdx.x * 8 + (threadIdx.x >> 5);
    if (v >= N) return;
    int lane = threadIdx.x & 63;
    int hl = lane & 31;
    int grp = hl >> 3, fl = hl & 7;
    float a[8];
    gatherH<64>(B16, sdst, row_ptr[v], row_ptr[v + 1], grp, fl, a);
    unsigned wA = tf_word((unsigned)v * 64u + 2u * (unsigned)hl);
    unsigned wB = tf_word((unsigned)v * 64u + 2u * (unsigned)hl + 1u);
    int base = (lane & 32) + 4 * fl;
    unsigned ww[8];
#pragma unroll
    for (int k = 0; k < 8; ++k) ww[k] = __shfl((k & 1) ? wB : wA, base + (k >> 1));
    if (grp == 0) {
        float dv = -dinv[v];
        const float* dp = D + (size_t)v * 64 + 8 * fl;
        float4 dA = *(const float4*)dp;
        float4 dB = *(const float4*)(dp + 4);
        float o[8];
        o[0] = fmaxf(fmaf(dv, a[0], dA.x), 0.0f);
        o[1] = fmaxf(fmaf(dv, a[1], dA.y), 0.0f);
        o[2] = fmaxf(fmaf(dv, a[2], dA.z), 0.0f);
        o[3] = fmaxf(fmaf(dv, a[3], dA.w), 0.0f);
        o[4] = fmaxf(fmaf(dv, a[4], dB.x), 0.0f);
        o[5] = fmaxf(fmaf(dv, a[5], dB.y), 0.0f);
        o[6] = fmaxf(fmaf(dv, a[6], dB.z), 0.0f);
        o[7] = fmaxf(fmaf(dv, a[7], dB.w), 0.0f);
#pragma unroll
        for (int k = 0; k < 8; ++k)
            o[k] = (ww[k] & 0x80000000u) ? 0.0f : o[k] * 2.0f;
        float* cp = C + (size_t)v * 64 + 8 * fl;
        *(float4*)cp = make_float4(o[0], o[1], o[2], o[3]);
        *(float4*)(cp + 4) = make_float4(o[4], o[5], o[6], o[7]);
    }
}

// Gather 3: R16[v] = bf16( dinv[v] * (D1[v] - 2*dinv[v]*sum D2'[c]) ), pre-scaled.
__global__ void __launch_bounds__(BLK) k_gath3(const unsigned short* __restrict__ B16,
                                               const float* __restrict__ P1,
                                               unsigned short* __restrict__ R16,
                                               const float* __restrict__ dinv,
                                               const int* __restrict__ row_ptr,
                                               const int* __restrict__ sdst,
                                               int N) {
    int v = blockIdx.x * 8 + (threadIdx.x >> 5);
    if (v >= N) return;
    int hl = threadIdx.x & 31;
    int grp = hl >> 2, fl = hl & 3;
    float a[8];
    gatherH<32>(B16, sdst, row_ptr[v], row_ptr[v + 1], grp, fl, a);
    if (grp == 0) {
        float di = dinv[v];
        float dv = -2.0f * di;
        const float* dp = P1 + (size_t)v * 32 + 8 * fl;
        float4 dA = *(const float4*)dp;
        float4 dB = *(const float4*)(dp + 4);
        uint4 o;
        o.x = pack2(di * fmaf(dv, a[0], dA.x), di * fmaf(dv, a[1], dA.y));
        o.y = pack2(di * fmaf(dv, a[2], dA.z), di * fmaf(dv, a[3], dA.w));
        o.z = pack2(di * fmaf(dv, a[4], dB.x), di * fmaf(dv, a[5], dB.y));
        o.w = pack2(di * fmaf(dv, a[6], dB.z), di * fmaf(dv, a[7], dB.w));
        *(uint4*)(R16 + (size_t)v * 32 + 8 * fl) = o;
    }
}

// Gather 4: out = log_softmax(D0 + b2 - dinv[v]*sum R16'[c]).
__global__ void __launch_bounds__(BLK) k_gath4(const unsigned short* __restrict__ R16,
                                               const float* __restrict__ P0,
                                               const float* __restrict__ dinv,
                                               const int* __restrict__ row_ptr,
                                               const int* __restrict__ sdst,
                                               const float* __restrict__ b2,
                                               int N, float* __restrict__ out) {
    int v = blockIdx.x * 8 + (threadIdx.x >> 5);
    if (v >= N) return;
    int hl = threadIdx.x & 31;
    int grp = hl >> 2, fl = hl & 3;
    float a[8];
    gatherH<32>(R16, sdst, row_ptr[v], row_ptr[v + 1], grp, fl, a);
    float dv = -dinv[v];
    const float* dp = P0 + (size_t)v * 32 + 8 * fl;
    float4 dA = *(const float4*)dp;
    float4 dB = *(const float4*)(dp + 4);
    const float* bp = b2 + 8 * fl;
    float4 bA = *(const float4*)bp;
    float4 bB = *(const float4*)(bp + 4);
    float o[8];
    o[0] = fmaf(dv, a[0], dA.x + bA.x);
    o[1] = fmaf(dv, a[1], dA.y + bA.y);
    o[2] = fmaf(dv, a[2], dA.z + bA.z);
    o[3] = fmaf(dv, a[3], dA.w + bA.w);
    o[4] = fmaf(dv, a[4], dB.x + bB.x);
    o[5] = fmaf(dv, a[5], dB.y + bB.y);
    o[6] = fmaf(dv, a[6], dB.z + bB.z);
    o[7] = fmaf(dv, a[7], dB.w + bB.w);
    float m = o[0];
#pragma unroll
    for (int k = 1; k < 8; ++k) m = fmaxf(m, o[k]);
    m = fmaxf(m, __shfl_xor(m, 1));
    m = fmaxf(m, __shfl_xor(m, 2));
    float s = 0.0f;
#pragma unroll
    for (int k = 0; k < 8; ++k) s += __expf(o[k] - m);
    s += __shfl_xor(s, 1);
    s += __shfl_xor(s, 2);
    float lse = m + __logf(s);
    if (grp == 0) {
        float* op = out + (size_t)v * 32 + 8 * fl;
        *(float4*)op = make_float4(o[0] - lse, o[1] - lse, o[2] - lse, o[3] - lse);
        *(float4*)(op + 4) = make_float4(o[4] - lse, o[5] - lse, o[6] - lse, o[7] - lse);
    }
}

extern "C" void kernel_launch(void* const* d_in, const int* in_sizes, int n_in,
                              void* d_out, int out_size, void* d_ws, size_t ws_size,
                              hipStream_t stream) {
    const float* x  = (const float*)d_in[0];
    const int* ei   = (const int*)d_in[1];
    const float* W1 = (const float*)d_in[2];
    const float* b1 = (const float*)d_in[3];
    const float* W2 = (const float*)d_in[4];
    const float* b2 = (const float*)d_in[5];
    float* out = (float*)d_out;

    const int N = in_sizes[0] / 64;
    const int E = in_sizes[1] / 2;
    const int NB = (N + ROWB - 1) >> RB_SHIFT;

    char* ws = (char*)d_ws;
    size_t off = 0;
    auto alloc = [&](size_t bytes) -> void* {
        void* p = ws + off;
        off = (off + bytes + 511) & ~(size_t)511;
        return p;
    };
    int*      flags   = (int*)alloc(16);
    int*      deg     = (int*)alloc((size_t)N * 4);
    float*    dinv    = (float*)alloc((size_t)N * 4);
    int*      row_ptr = (int*)alloc(((size_t)N + 1) * 4);
    int*      blk_sum = (int*)alloc(4096);
    int*      bcnt    = (int*)alloc((size_t)NB * 4);
    // Region shared over time: bdata (preproc) -> D (layer1 f32, N*64) ->
    // P0 || P1 (layer2 f32, each N*32; written by dense3b after D is dead).
    size_t dbytes = (size_t)N * 64 * 4;
    size_t bdbytes = (size_t)NB * BCAP * 4;
    unsigned* bdata = (unsigned*)alloc(dbytes > bdbytes ? dbytes : bdbytes);
    float*    D     = (float*)bdata;
    float*    P0    = (float*)bdata;
    float*    P1    = P0 + (size_t)N * 32;
    int*      sdst  = (int*)alloc((size_t)E * 4);
    float*    C     = (float*)alloc((size_t)N * 64 * 4);
    unsigned short* B16 = (unsigned short*)alloc((size_t)N * 64 * 2);
    // C16 (layer-1 gather source, dead after gath1) shares with R16 (layer-2).
    unsigned short* C16 = (unsigned short*)alloc((size_t)N * 64 * 2);
    unsigned short* R16 = C16;
    unsigned short* wt1 = (unsigned short*)alloc(12288 * 2);
    unsigned short* wt2 = (unsigned short*)alloc(6144 * 2);

    hipMemsetAsync(bcnt, 0, (size_t)NB * 4, stream);

    const int gW8 = (N + 7) / 8;
    const int gDM = (N + 127) / 128;
    const int nb = (N + SCAN_CHUNK - 1) / SCAN_CHUNK;
    const int gBin = (E + CHUNK - 1) / CHUNK;

    k_wprep<<<72, 256, 0, stream>>>(W1, W2, wt1, wt2);
    k_detect<<<1, 256, 0, stream>>>(ei, flags);
    k_bin<<<gBin, 256, 0, stream>>>(ei, E, flags, bcnt, bdata, NB);
    k_hist2<<<NB, 256, 0, stream>>>(bdata, bcnt, N, deg, dinv);
    k_scanA<<<nb, SCAN_CHUNK, 0, stream>>>(deg, N, blk_sum);
    k_scanB<<<1, 1024, 0, stream>>>(blk_sum, nb);
    k_scanC<<<nb, SCAN_CHUNK, 0, stream>>>(deg, N, E, blk_sum, row_ptr);
    k_place<<<NB, 256, 0, stream>>>(bdata, bcnt, row_ptr, N, sdst);

    // Layer 1: B16=bf16(x@W1[1]), C16=bf16(dinv*(x@W1[2])), D=x@(W1[0]-W1[2])+b1;
    // B16 = dinv*(B16 - 2*dinv*S'(C16)); C = drop(relu(D - dinv*S'(B16)))
    k_dense3<<<gDM, 512, 0, stream>>>(x, wt1, b1, dinv, N, B16, C16, D);
    k_gath1<<<gW8, BLK, 0, stream>>>(C16, B16, dinv, row_ptr, sdst, N);
    k_gath2<<<gW8, BLK, 0, stream>>>(D, B16, C, dinv, row_ptr, sdst, N);

    // Layer 2: D0->P0, D1->P1 (f32 pitch 32); D2 pre-scaled bf16 in B16 (pitch 32);
    // R16 = dinv*(D1 - 2*dinv*S'(D2)); out = lsm(D0 + b2 - dinv*S'(R16))
    k_dense3b<<<gDM, 512, 0, stream>>>(wt2, dinv, N, B16, C, P0, P1);
    k_gath3<<<gW8, BLK, 0, stream>>>(B16, P1, R16, dinv, row_ptr, sdst, N);
    k_gath4<<<gW8, BLK, 0, stream>>>(R16, P0, dinv, row_ptr, sdst, b2, N, out);
}